// Round 20
// baseline (203.091 us; speedup 1.0000x reference)
//
#include <hip/hip_runtime.h>
#include <hip/hip_bf16.h>
#include <stdint.h>

#define BB 64
#define DD 2048
#define VV 50257
#define VP 50260     // padded row stride (mult of 4) for partial/logits
#define NQ 12565     // per-row reduce quads: 12564 float4 + 1 tail elem
#define RB 13        // reduce blocks per row
#define QPB 967      // quads per reduce block (13*967 >= 12565)
#define NB 4096      // histogram bins
#define MAXC 2048    // boundary-bin collect capacity
#define QS 8         // gumbel-argmax blocks per row
#define QCH 6283     // ceil(VV/QS)
#define SK 8         // MFMA split-K slices (R20: 4->8, 6 waves/SIMD)

typedef __attribute__((ext_vector_type(8))) short short8;
typedef __attribute__((ext_vector_type(4))) float f32x4;
typedef float f32x4u __attribute__((vector_size(16), aligned(4)));  // 4B-aligned vec load

struct U2 { unsigned x, y; };

__device__ __forceinline__ unsigned rotl32(unsigned v, int r) {
  return (v << r) | (v >> (32 - r));
}

// JAX threefry2x32 (jax/_src/prng.py lowering), 20 rounds.
__device__ __forceinline__ U2 threefry2x32(unsigned k0, unsigned k1,
                                           unsigned x0, unsigned x1) {
  unsigned k2 = k0 ^ k1 ^ 0x1BD11BDAu;
  x0 += k0; x1 += k1;
#define TF_R4(r1, r2, r3, r4)                         \
  x0 += x1; x1 = rotl32(x1, r1); x1 ^= x0;            \
  x0 += x1; x1 = rotl32(x1, r2); x1 ^= x0;            \
  x0 += x1; x1 = rotl32(x1, r3); x1 ^= x0;            \
  x0 += x1; x1 = rotl32(x1, r4); x1 ^= x0;
  TF_R4(13, 15, 26, 6)   x0 += k1; x1 += k2 + 1u;
  TF_R4(17, 29, 16, 24)  x0 += k2; x1 += k0 + 2u;
  TF_R4(13, 15, 26, 6)   x0 += k0; x1 += k1 + 3u;
  TF_R4(17, 29, 16, 24)  x0 += k1; x1 += k2 + 4u;
  TF_R4(13, 15, 26, 6)   x0 += k2; x1 += k0 + 5u;
#undef TF_R4
  U2 r; r.x = x0; r.y = x1; return r;
}

// VALIDATED (R5): partitionable threefry bits = XOR-fold of both cipher words,
// counter (hi=0, lo=e), key (0, 42).
__device__ __forceinline__ unsigned jax_random_bits(unsigned e) {
  U2 r = threefry2x32(0u, 42u, 0u, e);
  return r.x ^ r.y;
}

__device__ __forceinline__ unsigned mono_key(float zi) {
  unsigned bb = __float_as_uint(zi);
  return bb ^ ((bb >> 31) ? 0xFFFFFFFFu : 0x80000000u);
}
__device__ __forceinline__ float mono_key_inv(unsigned k) {
  return __uint_as_float((k >> 31) ? (k ^ 0x80000000u) : ~k);
}

// HW bf16 conversion (R13-validated; compiler fuses into v_cvt_pk_bf16_f32).
__device__ __forceinline__ unsigned short f2bf_hw(float f) {
  __hip_bfloat16 b = __float2bfloat16(f);
  unsigned short u;
  __builtin_memcpy(&u, &b, 2);
  return u;
}
__device__ __forceinline__ float bf2f(unsigned short h) {
  return __uint_as_float(((unsigned)h) << 16);
}

// Pack x into MFMA-A-fragment-ready bf16 hi/lo arrays; also zero-init the
// rowmax array (stream-ordered before reduce_bias uses it).
__global__ __launch_bounds__(256) void pack_x_kernel(
    const float* __restrict__ x, unsigned short* __restrict__ xh,
    unsigned short* __restrict__ xl, unsigned* __restrict__ rowmax) {
  if (blockIdx.x == 0 && threadIdx.x < BB) rowmax[threadIdx.x] = 0u;
  int i = blockIdx.x * 256 + threadIdx.x;     // 64 rows * 256 chunks
  if (i >= 64 * 256) return;
  int b = i >> 8;
  int c = i & 255;
  const float* xp = x + b * 2048 + c * 8;
  short8 hv, lv;
#pragma unroll
  for (int j = 0; j < 8; ++j) {
    float f = xp[j];
    unsigned short h = f2bf_hw(f);
    hv[j] = (short)h;
    lv[j] = (short)f2bf_hw(f - bf2f(h));
  }
  size_t p = ((size_t)c * 64 + b) * 8;
  *(short8*)(xh + p) = hv;
  *(short8*)(xl + p) = lv;
}

// MFMA GEMM, bf16-split, split-K=8, INTERLEAVED B-fragments (R16-validated
// request-width layout; rolled kss loop). SK=8 -> 6288 waves = 6 waves/SIMD
// for latency hiding (SK=4 had only 3/SIMD; issue math says ~60% stall).
// Slice s covers ks [s*8, +8).
__global__ __launch_bounds__(256, 1) void gemm_mfma_kernel(
    const unsigned short* __restrict__ xh, const unsigned short* __restrict__ xl,
    const float* __restrict__ W, float* __restrict__ partial) {
  const int wave = threadIdx.x >> 6;
  const int lane = threadIdx.x & 63;
  const int lo = lane & 15, hi = lane >> 4;
  const int v0w = blockIdx.x * 256 + wave * 64;   // wave's 64-col window
  const int vC = v0w + 4 * lo;                    // lane's 4-col base
  const int ks0 = blockIdx.y * (64 / SK);
  const bool edge = (v0w + 64 > VV);

  f32x4 a00 = {0,0,0,0}, a01 = {0,0,0,0}, a02 = {0,0,0,0}, a03 = {0,0,0,0};
  f32x4 a10 = {0,0,0,0}, a11 = {0,0,0,0}, a12 = {0,0,0,0}, a13 = {0,0,0,0};
  f32x4 a20 = {0,0,0,0}, a21 = {0,0,0,0}, a22 = {0,0,0,0}, a23 = {0,0,0,0};
  f32x4 a30 = {0,0,0,0}, a31 = {0,0,0,0}, a32 = {0,0,0,0}, a33 = {0,0,0,0};

  for (int kss = 0; kss < 64 / SK; ++kss) {
    const int ks = ks0 + kss;
    const float* wb = W + (size_t)(ks * 32 + hi * 8) * VV;
    f32x4u wq[8];
    if (!edge) {
#pragma unroll
      for (int j = 0; j < 8; ++j)
        wq[j] = *(const f32x4u*)(wb + (size_t)j * VV + vC);
    } else {
#pragma unroll
      for (int j = 0; j < 8; ++j) {
#pragma unroll
        for (int c = 0; c < 4; ++c) {
          int col = vC + c; if (col > VV - 1) col = VV - 1;
          wq[j][c] = wb[(size_t)j * VV + col];
        }
      }
    }
    short8 bh0, bh1, bh2, bh3, bl0, bl1, bl2, bl3;
#pragma unroll
    for (int j = 0; j < 8; ++j) {
      unsigned short h;
      h = f2bf_hw(wq[j][0]); bh0[j] = (short)h; bl0[j] = (short)f2bf_hw(wq[j][0] - bf2f(h));
      h = f2bf_hw(wq[j][1]); bh1[j] = (short)h; bl1[j] = (short)f2bf_hw(wq[j][1] - bf2f(h));
      h = f2bf_hw(wq[j][2]); bh2[j] = (short)h; bl2[j] = (short)f2bf_hw(wq[j][2] - bf2f(h));
      h = f2bf_hw(wq[j][3]); bh3[j] = (short)h; bl3[j] = (short)f2bf_hw(wq[j][3] - bf2f(h));
    }
    const int chunk = ks * 4 + hi;
#define DO_RT(RT, A0, A1, A2, A3)                                           \
    {                                                                       \
      size_t p = ((size_t)chunk * 64 + (RT) * 16 + lo) * 8;                 \
      short8 ah = *(const short8*)(xh + p);                                 \
      short8 al = *(const short8*)(xl + p);                                 \
      A0 = __builtin_amdgcn_mfma_f32_16x16x32_bf16(ah, bh0, A0, 0, 0, 0);   \
      A0 = __builtin_amdgcn_mfma_f32_16x16x32_bf16(al, bh0, A0, 0, 0, 0);   \
      A0 = __builtin_amdgcn_mfma_f32_16x16x32_bf16(ah, bl0, A0, 0, 0, 0);   \
      A1 = __builtin_amdgcn_mfma_f32_16x16x32_bf16(ah, bh1, A1, 0, 0, 0);   \
      A1 = __builtin_amdgcn_mfma_f32_16x16x32_bf16(al, bh1, A1, 0, 0, 0);   \
      A1 = __builtin_amdgcn_mfma_f32_16x16x32_bf16(ah, bl1, A1, 0, 0, 0);   \
      A2 = __builtin_amdgcn_mfma_f32_16x16x32_bf16(ah, bh2, A2, 0, 0, 0);   \
      A2 = __builtin_amdgcn_mfma_f32_16x16x32_bf16(al, bh2, A2, 0, 0, 0);   \
      A2 = __builtin_amdgcn_mfma_f32_16x16x32_bf16(ah, bl2, A2, 0, 0, 0);   \
      A3 = __builtin_amdgcn_mfma_f32_16x16x32_bf16(ah, bh3, A3, 0, 0, 0);   \
      A3 = __builtin_amdgcn_mfma_f32_16x16x32_bf16(al, bh3, A3, 0, 0, 0);   \
      A3 = __builtin_amdgcn_mfma_f32_16x16x32_bf16(ah, bl3, A3, 0, 0, 0);   \
    }
    DO_RT(0, a00, a10, a20, a30)
    DO_RT(1, a01, a11, a21, a31)
    DO_RT(2, a02, a12, a22, a32)
    DO_RT(3, a03, a13, a23, a33)
#undef DO_RT
  }

  float* pp = partial + (size_t)blockIdx.y * BB * VP;
#define ST_RT(RT, A0, A1, A2, A3)                                           \
  {                                                                         \
    _Pragma("unroll")                                                       \
    for (int r = 0; r < 4; ++r) {                                           \
      int row = (RT) * 16 + hi * 4 + r;                                     \
      float4 o; o.x = A0[r]; o.y = A1[r]; o.z = A2[r]; o.w = A3[r];         \
      if (!edge) {                                                          \
        *(float4*)(pp + (size_t)row * VP + vC) = o;                         \
      } else {                                                              \
        if (vC + 0 < VV) pp[(size_t)row * VP + vC + 0] = o.x;               \
        if (vC + 1 < VV) pp[(size_t)row * VP + vC + 1] = o.y;               \
        if (vC + 2 < VV) pp[(size_t)row * VP + vC + 2] = o.z;               \
        if (vC + 3 < VV) pp[(size_t)row * VP + vC + 3] = o.w;               \
      }                                                                     \
    }                                                                       \
  }
  ST_RT(0, a00, a10, a20, a30)
  ST_RT(1, a01, a11, a21, a31)
  ST_RT(2, a02, a12, a22, a32)
  ST_RT(3, a03, a13, a23, a33)
#undef ST_RT
}

// Reduce + bias into padded logits, one row-part per block (grid RB x BB),
// plus fused per-row max -> atomicMax(rowmax[row], mono_key) (R17/R18-
// validated; order-independent => deterministic).
__global__ __launch_bounds__(256) void reduce_bias_kernel(
    const float* __restrict__ partial, const float* __restrict__ bias,
    float* __restrict__ logits, unsigned* __restrict__ rowmax) {
  __shared__ float smax[256];
  const int b = blockIdx.y;
  const int q0 = blockIdx.x * QPB;
  const int q1 = (q0 + QPB < NQ) ? q0 + QPB : NQ;
  float mx = -3.4e38f;
  for (int q = q0 + threadIdx.x; q < q1; q += 256) {
    if (q < NQ - 1) {
      int v = q * 4;
      float4 acc = *(const float4*)(bias + v);
#pragma unroll
      for (int s = 0; s < SK; ++s) {
        float4 p = *(const float4*)(partial + ((size_t)s * BB + b) * VP + v);
        acc.x += p.x; acc.y += p.y; acc.z += p.z; acc.w += p.w;
      }
      *(float4*)(logits + (size_t)b * VP + v) = acc;
      mx = fmaxf(mx, fmaxf(fmaxf(acc.x, acc.y), fmaxf(acc.z, acc.w)));
    } else {
      int v = VV - 1;   // 50256 tail element
      float acc = bias[v];
#pragma unroll
      for (int s = 0; s < SK; ++s)
        acc += partial[((size_t)s * BB + b) * VP + v];
      logits[(size_t)b * VP + v] = acc;
      mx = fmaxf(mx, acc);
    }
  }
  smax[threadIdx.x] = mx; __syncthreads();
  for (int s = 128; s > 0; s >>= 1) {
    if (threadIdx.x < s) smax[threadIdx.x] = fmaxf(smax[threadIdx.x], smax[threadIdx.x + s]);
    __syncthreads();
  }
  if (threadIdx.x == 0) atomicMax(rowmax + b, mono_key(smax[0]));
}

// Per row: histogram (m from fused rowmax) -> boundary-bin exact prefix sums
// -> tstar[row]. Semantics unchanged from R6-validated chain.
__global__ __launch_bounds__(1024) void nucleus_tstar_kernel(
    const float* __restrict__ logits, const unsigned* __restrict__ rowmax,
    unsigned* __restrict__ tstar_out, unsigned long long* __restrict__ pack) {
  __shared__ double sd[1024];
  __shared__ unsigned su[1024];
  __shared__ double bins[NB];
  __shared__ int cidx[MAXC];
  __shared__ unsigned ckey[MAXC];
  __shared__ double cw[MAXC];
  __shared__ int ccount;
  __shared__ int sh_chunk;
  __shared__ int sh_bstar;
  __shared__ double sh_sabove;

  const int row = blockIdx.x;
  const int tid = threadIdx.x;
  const float* z = logits + (size_t)row * VP;
  const float m = mono_key_inv(rowmax[row]);

  for (int i = tid; i < NB; i += 1024) bins[i] = 0.0;
  if (tid == 0) { ccount = 0; sh_chunk = -1; sh_bstar = -1; }
  __syncthreads();

  // histogram of exp(z-m) binned by (m-z)*256
  for (int i = tid; i < VV; i += 1024) {
    float zi = z[i];
    int bin = (int)((m - zi) * 256.0f);
    bin = (bin < 0) ? 0 : ((bin > NB - 1) ? NB - 1 : bin);
    atomicAdd(&bins[bin], (double)expf(zi - m));
  }
  __syncthreads();

  // inclusive scan over 1024 chunk-sums (4 bins/chunk), f64
  {
    double c = bins[4 * tid] + bins[4 * tid + 1] + bins[4 * tid + 2] + bins[4 * tid + 3];
    sd[tid] = c; __syncthreads();
    for (int off = 1; off < 1024; off <<= 1) {
      double vv = (tid >= off) ? sd[tid - off] : 0.0;
      __syncthreads();
      sd[tid] += vv;
      __syncthreads();
    }
  }
  const double Z = sd[1023];
  const double C = (double)0.9f * Z;

  if (sd[tid] > C && (tid == 0 || sd[tid - 1] <= C)) sh_chunk = tid;
  __syncthreads();
  if (tid == 0) {
    int tc = sh_chunk;
    if (tc >= 0) {
      double run = (tc > 0) ? sd[tc - 1] : 0.0;
      for (int k = 0; k < 4; ++k) {
        double bw = bins[4 * tc + k];
        if (run + bw > C) { sh_bstar = 4 * tc + k; sh_sabove = run; break; }
        run += bw;
      }
    }
  }
  __syncthreads();
  const int bstar = sh_bstar;
  unsigned tkey = 0u;

  if (bstar >= 0) {
    const double Sab = sh_sabove;
    // collect boundary-bin elements
    for (int i = tid; i < VV; i += 1024) {
      float zi = z[i];
      int bin = (int)((m - zi) * 256.0f);
      bin = (bin < 0) ? 0 : ((bin > NB - 1) ? NB - 1 : bin);
      if (bin == bstar) {
        int slot = atomicAdd(&ccount, 1);
        if (slot < MAXC) {
          ckey[slot] = mono_key(zi);
          cidx[slot] = i;
          cw[slot] = (double)expf(zi - m);
        }
      }
    }
    __syncthreads();
    int n = ccount; if (n > MAXC) n = MAXC;
    // kept iff exclusive prefix (in (key desc, idx asc) order) <= C
    unsigned mk = 0xFFFFFFFFu;
    for (int i = tid; i < n; i += 1024) {
      unsigned ki = ckey[i]; int ii = cidx[i];
      double T = Sab;
      for (int j = 0; j < n; ++j) {
        unsigned kj = ckey[j];
        if (kj > ki || (kj == ki && cidx[j] < ii)) T += cw[j];
      }
      if (T <= C) mk = (ki < mk) ? ki : mk;
    }
    su[tid] = mk; __syncthreads();
    for (int s = 512; s > 0; s >>= 1) {
      if (tid < s) su[tid] = min(su[tid], su[tid + s]);
      __syncthreads();
    }
    tkey = su[0];
  }
  if (tid == 0) { tstar_out[row] = tkey; pack[row] = 0ull; }
}

// Gumbel argmax over kept tokens, 8 blocks/row; combine via atomicMax(u64)
// on pack = mono(best)<<32 | (~idx) — order-independent (deterministic) and
// reproduces (best desc, idx asc) tie-break exactly.
__global__ __launch_bounds__(1024) void gumbel_kernel(
    const float* __restrict__ logits, const unsigned* __restrict__ tstar_arr,
    unsigned long long* __restrict__ pack) {
  __shared__ float sf[1024];
  __shared__ int si[1024];
  const int row = blockIdx.x >> 3;
  const int q = blockIdx.x & 7;
  const int tid = threadIdx.x;
  const unsigned tstar = tstar_arr[row];
  const float* z = logits + (size_t)row * VP;
  const int i0 = q * QCH;
  const int i1 = (i0 + QCH < VV) ? (i0 + QCH) : VV;

  float best = -3.4e38f; int bidx = 0x7FFFFFFF;
  for (int i = i0 + tid; i < i1; i += 1024) {
    float zi = z[i];
    if (mono_key(zi) < tstar) continue;
    unsigned e = (unsigned)row * (unsigned)VV + (unsigned)i;   // logical VV!
    unsigned bits = jax_random_bits(e);
    float f = __uint_as_float((bits >> 9) | 0x3F800000u) - 1.0f;
    float u = fmaxf(1.17549435082228750797e-38f, f);
    float g = -logf(-logf(u));
    float sc = zi + g;
    if (sc > best) { best = sc; bidx = i; }
  }
  sf[tid] = best; si[tid] = bidx; __syncthreads();
  for (int s = 512; s > 0; s >>= 1) {
    if (tid < s) {
      float ob = sf[tid + s]; int oi = si[tid + s];
      if (ob > sf[tid] || (ob == sf[tid] && oi < si[tid])) {
        sf[tid] = ob; si[tid] = oi;
      }
    }
    __syncthreads();
  }
  if (tid == 0 && si[0] != 0x7FFFFFFF) {
    unsigned long long p = ((unsigned long long)mono_key(sf[0]) << 32) |
                           (unsigned long long)(0xFFFFFFFFu - (unsigned)si[0]);
    atomicMax(pack + row, p);
  }
}

__global__ __launch_bounds__(64) void unpack_kernel(
    const unsigned long long* __restrict__ pack, int* __restrict__ out) {
  int r = threadIdx.x;
  if (r < BB) out[r] = (int)(0xFFFFFFFFu - (unsigned)(pack[r] & 0xFFFFFFFFull));
}

extern "C" void kernel_launch(void* const* d_in, const int* in_sizes, int n_in,
                              void* d_out, int out_size, void* d_ws, size_t ws_size,
                              hipStream_t stream) {
  const float* x = (const float*)d_in[0];
  const float* W = (const float*)d_in[1];
  const float* bias = (const float*)d_in[2];
  int* out = (int*)d_out;
  char* ws = (char*)d_ws;

  unsigned short* xh = (unsigned short*)ws;              // 262144 B
  unsigned short* xl = (unsigned short*)(ws + 262144);   // 262144 B
  float* logits = (float*)(ws + 524288);                 // BB*VP*4 = 12866560
  float* partial = (float*)(ws + 13390848);              // SK*BB*VP*4 = 102932480
  unsigned* tstar = (unsigned*)(ws + 116323328);         // 256 B
  unsigned long long* pack = (unsigned long long*)(ws + 116323584);  // 512 B
  unsigned* rowmax = (unsigned*)(ws + 116324096);        // 256 B

  pack_x_kernel<<<64, 256, 0, stream>>>(x, xh, xl, rowmax);
  const int cblocks = (VV + 255) / 256;   // 197 col-blocks of 256 cols
  dim3 g(cblocks, SK);
  gemm_mfma_kernel<<<g, 256, 0, stream>>>(xh, xl, W, partial);
  dim3 gr(RB, BB);
  reduce_bias_kernel<<<gr, 256, 0, stream>>>(partial, bias, logits, rowmax);
  nucleus_tstar_kernel<<<BB, 1024, 0, stream>>>(logits, rowmax, tstar, pack);
  gumbel_kernel<<<BB * QS, 1024, 0, stream>>>(logits, tstar, pack);
  unpack_kernel<<<1, 64, 0, stream>>>(pack, out);
}

// Round 21
// 180.968 us; speedup vs baseline: 1.1223x; 1.1223x over previous
//
#include <hip/hip_runtime.h>
#include <hip/hip_bf16.h>
#include <stdint.h>

#define BB 64
#define DD 2048
#define VV 50257
#define VP 50260     // padded row stride (mult of 4) for logits
#define NB 4096      // histogram bins
#define MAXC 2048    // boundary-bin collect capacity
#define QS 8         // gumbel-argmax blocks per row
#define QCH 6283     // ceil(VV/QS)

typedef __attribute__((ext_vector_type(8))) short short8;
typedef __attribute__((ext_vector_type(4))) float f32x4;
typedef float f32x4u __attribute__((vector_size(16), aligned(4)));  // 4B-aligned vec load

struct U2 { unsigned x, y; };

__device__ __forceinline__ unsigned rotl32(unsigned v, int r) {
  return (v << r) | (v >> (32 - r));
}

// JAX threefry2x32 (jax/_src/prng.py lowering), 20 rounds.
__device__ __forceinline__ U2 threefry2x32(unsigned k0, unsigned k1,
                                           unsigned x0, unsigned x1) {
  unsigned k2 = k0 ^ k1 ^ 0x1BD11BDAu;
  x0 += k0; x1 += k1;
#define TF_R4(r1, r2, r3, r4)                         \
  x0 += x1; x1 = rotl32(x1, r1); x1 ^= x0;            \
  x0 += x1; x1 = rotl32(x1, r2); x1 ^= x0;            \
  x0 += x1; x1 = rotl32(x1, r3); x1 ^= x0;            \
  x0 += x1; x1 = rotl32(x1, r4); x1 ^= x0;
  TF_R4(13, 15, 26, 6)   x0 += k1; x1 += k2 + 1u;
  TF_R4(17, 29, 16, 24)  x0 += k2; x1 += k0 + 2u;
  TF_R4(13, 15, 26, 6)   x0 += k0; x1 += k1 + 3u;
  TF_R4(17, 29, 16, 24)  x0 += k1; x1 += k2 + 4u;
  TF_R4(13, 15, 26, 6)   x0 += k2; x1 += k0 + 5u;
#undef TF_R4
  U2 r; r.x = x0; r.y = x1; return r;
}

// VALIDATED (R5): partitionable threefry bits = XOR-fold of both cipher words,
// counter (hi=0, lo=e), key (0, 42).
__device__ __forceinline__ unsigned jax_random_bits(unsigned e) {
  U2 r = threefry2x32(0u, 42u, 0u, e);
  return r.x ^ r.y;
}

__device__ __forceinline__ unsigned mono_key(float zi) {
  unsigned bb = __float_as_uint(zi);
  return bb ^ ((bb >> 31) ? 0xFFFFFFFFu : 0x80000000u);
}

// HW bf16 conversion (R13-validated; compiler fuses into v_cvt_pk_bf16_f32).
__device__ __forceinline__ unsigned short f2bf_hw(float f) {
  __hip_bfloat16 b = __float2bfloat16(f);
  unsigned short u;
  __builtin_memcpy(&u, &b, 2);
  return u;
}
__device__ __forceinline__ float bf2f(unsigned short h) {
  return __uint_as_float(((unsigned)h) << 16);
}

// Pack x into MFMA-A-fragment-ready bf16 hi/lo arrays.
__global__ __launch_bounds__(256) void pack_x_kernel(
    const float* __restrict__ x, unsigned short* __restrict__ xh,
    unsigned short* __restrict__ xl) {
  int i = blockIdx.x * 256 + threadIdx.x;     // 64 rows * 256 chunks
  if (i >= 64 * 256) return;
  int b = i >> 8;
  int c = i & 255;
  const float* xp = x + b * 2048 + c * 8;
  short8 hv, lv;
#pragma unroll
  for (int j = 0; j < 8; ++j) {
    float f = xp[j];
    unsigned short h = f2bf_hw(f);
    hv[j] = (short)h;
    lv[j] = (short)f2bf_hw(f - bf2f(h));
  }
  size_t p = ((size_t)c * 64 + b) * 8;
  *(short8*)(xh + p) = hv;
  *(short8*)(xl + p) = lv;
}

// MFMA GEMM, bf16-split, INTERLEAVED B-fragments (R16-validated inner loop,
// byte-identical), with IN-BLOCK split-K: block owns one 64-col window;
// wave w computes ks in [w*16, w*16+16). Epilogue: 4-phase serialized LDS
// accumulation (deterministic fixed order) + bias-fused logits write.
// Deletes the 103 MB partial round-trip and the reduce kernel (R20 showed
// the gemm is memory-system-bound; this removes structural traffic).
__global__ __launch_bounds__(256, 1) void gemm_mfma_kernel(
    const unsigned short* __restrict__ xh, const unsigned short* __restrict__ xl,
    const float* __restrict__ W, const float* __restrict__ bias,
    float* __restrict__ logits) {
  __shared__ float lacc[64][68];                  // stride-68 pad: <=4-way banks
  const int wave = threadIdx.x >> 6;
  const int lane = threadIdx.x & 63;
  const int lo = lane & 15, hi = lane >> 4;
  const int v0blk = blockIdx.x * 64;              // block's 64-col window
  const int vC = v0blk + 4 * lo;                  // lane's 4-col base
  const int ks0 = wave * 16;                      // per-wave K-quarter
  const bool edge = (v0blk + 64 > VV);

  f32x4 a00 = {0,0,0,0}, a01 = {0,0,0,0}, a02 = {0,0,0,0}, a03 = {0,0,0,0};
  f32x4 a10 = {0,0,0,0}, a11 = {0,0,0,0}, a12 = {0,0,0,0}, a13 = {0,0,0,0};
  f32x4 a20 = {0,0,0,0}, a21 = {0,0,0,0}, a22 = {0,0,0,0}, a23 = {0,0,0,0};
  f32x4 a30 = {0,0,0,0}, a31 = {0,0,0,0}, a32 = {0,0,0,0}, a33 = {0,0,0,0};

  for (int kss = 0; kss < 16; ++kss) {
    const int ks = ks0 + kss;
    const float* wb = W + (size_t)(ks * 32 + hi * 8) * VV;
    f32x4u wq[8];
    if (!edge) {
#pragma unroll
      for (int j = 0; j < 8; ++j)
        wq[j] = *(const f32x4u*)(wb + (size_t)j * VV + vC);
    } else {
#pragma unroll
      for (int j = 0; j < 8; ++j) {
#pragma unroll
        for (int c = 0; c < 4; ++c) {
          int col = vC + c; if (col > VV - 1) col = VV - 1;
          wq[j][c] = wb[(size_t)j * VV + col];
        }
      }
    }
    short8 bh0, bh1, bh2, bh3, bl0, bl1, bl2, bl3;
#pragma unroll
    for (int j = 0; j < 8; ++j) {
      unsigned short h;
      h = f2bf_hw(wq[j][0]); bh0[j] = (short)h; bl0[j] = (short)f2bf_hw(wq[j][0] - bf2f(h));
      h = f2bf_hw(wq[j][1]); bh1[j] = (short)h; bl1[j] = (short)f2bf_hw(wq[j][1] - bf2f(h));
      h = f2bf_hw(wq[j][2]); bh2[j] = (short)h; bl2[j] = (short)f2bf_hw(wq[j][2] - bf2f(h));
      h = f2bf_hw(wq[j][3]); bh3[j] = (short)h; bl3[j] = (short)f2bf_hw(wq[j][3] - bf2f(h));
    }
    const int chunk = ks * 4 + hi;
#define DO_RT(RT, A0, A1, A2, A3)                                           \
    {                                                                       \
      size_t p = ((size_t)chunk * 64 + (RT) * 16 + lo) * 8;                 \
      short8 ah = *(const short8*)(xh + p);                                 \
      short8 al = *(const short8*)(xl + p);                                 \
      A0 = __builtin_amdgcn_mfma_f32_16x16x32_bf16(ah, bh0, A0, 0, 0, 0);   \
      A0 = __builtin_amdgcn_mfma_f32_16x16x32_bf16(al, bh0, A0, 0, 0, 0);   \
      A0 = __builtin_amdgcn_mfma_f32_16x16x32_bf16(ah, bl0, A0, 0, 0, 0);   \
      A1 = __builtin_amdgcn_mfma_f32_16x16x32_bf16(ah, bh1, A1, 0, 0, 0);   \
      A1 = __builtin_amdgcn_mfma_f32_16x16x32_bf16(al, bh1, A1, 0, 0, 0);   \
      A1 = __builtin_amdgcn_mfma_f32_16x16x32_bf16(ah, bl1, A1, 0, 0, 0);   \
      A2 = __builtin_amdgcn_mfma_f32_16x16x32_bf16(ah, bh2, A2, 0, 0, 0);   \
      A2 = __builtin_amdgcn_mfma_f32_16x16x32_bf16(al, bh2, A2, 0, 0, 0);   \
      A2 = __builtin_amdgcn_mfma_f32_16x16x32_bf16(ah, bl2, A2, 0, 0, 0);   \
      A3 = __builtin_amdgcn_mfma_f32_16x16x32_bf16(ah, bh3, A3, 0, 0, 0);   \
      A3 = __builtin_amdgcn_mfma_f32_16x16x32_bf16(al, bh3, A3, 0, 0, 0);   \
      A3 = __builtin_amdgcn_mfma_f32_16x16x32_bf16(ah, bl3, A3, 0, 0, 0);   \
    }
    DO_RT(0, a00, a10, a20, a30)
    DO_RT(1, a01, a11, a21, a31)
    DO_RT(2, a02, a12, a22, a32)
    DO_RT(3, a03, a13, a23, a33)
#undef DO_RT
  }

  // 4-phase serialized LDS accumulation: wave 0 stores, waves 1-3 add.
  // Fixed order -> deterministic, bit-identical across runs.
#define LACC_RT(RT, A0, A1, A2, A3, FIRST)                                  \
  {                                                                         \
    _Pragma("unroll")                                                       \
    for (int r = 0; r < 4; ++r) {                                           \
      int row = (RT) * 16 + hi * 4 + r;                                     \
      float* p = &lacc[row][4 * lo];                                        \
      if (FIRST) { p[0] = A0[r]; p[1] = A1[r]; p[2] = A2[r]; p[3] = A3[r]; }\
      else { p[0] += A0[r]; p[1] += A1[r]; p[2] += A2[r]; p[3] += A3[r]; }  \
    }                                                                       \
  }
  for (int w = 0; w < 4; ++w) {
    if (wave == w) {
      if (w == 0) {
        LACC_RT(0, a00, a10, a20, a30, true)
        LACC_RT(1, a01, a11, a21, a31, true)
        LACC_RT(2, a02, a12, a22, a32, true)
        LACC_RT(3, a03, a13, a23, a33, true)
      } else {
        LACC_RT(0, a00, a10, a20, a30, false)
        LACC_RT(1, a01, a11, a21, a31, false)
        LACC_RT(2, a02, a12, a22, a32, false)
        LACC_RT(3, a03, a13, a23, a33, false)
      }
    }
    __syncthreads();
  }
#undef LACC_RT

  // bias-fused logits write: 4096 elems / 256 thr = 4 float4 each.
#pragma unroll
  for (int k = 0; k < 4; ++k) {
    int q = (int)threadIdx.x + k * 256;   // 0..1023
    int row = q >> 4;
    int c4 = (q & 15) * 4;
    int col = v0blk + c4;
    float4 s = *(float4*)&lacc[row][c4];
    if (!edge) {
      float4 bv = *(const float4*)(bias + col);
      s.x += bv.x; s.y += bv.y; s.z += bv.z; s.w += bv.w;
      *(float4*)(logits + (size_t)row * VP + col) = s;
    } else {
      if (col + 0 < VV) logits[(size_t)row * VP + col + 0] = s.x + bias[col + 0];
      if (col + 1 < VV) logits[(size_t)row * VP + col + 1] = s.y + bias[col + 1];
      if (col + 2 < VV) logits[(size_t)row * VP + col + 2] = s.z + bias[col + 2];
      if (col + 3 < VV) logits[(size_t)row * VP + col + 3] = s.w + bias[col + 3];
    }
  }
}

// Per row: max -> histogram -> boundary-bin exact prefix sums -> tstar[row].
// (Byte-exact R16-measured tail.)
__global__ __launch_bounds__(1024) void nucleus_tstar_kernel(
    const float* __restrict__ logits, unsigned* __restrict__ tstar_out,
    unsigned long long* __restrict__ pack) {
  __shared__ double sd[1024];
  __shared__ float sf[1024];
  __shared__ unsigned su[1024];
  __shared__ double bins[NB];
  __shared__ int cidx[MAXC];
  __shared__ unsigned ckey[MAXC];
  __shared__ double cw[MAXC];
  __shared__ int ccount;
  __shared__ int sh_chunk;
  __shared__ int sh_bstar;
  __shared__ double sh_sabove;

  const int row = blockIdx.x;
  const int tid = threadIdx.x;
  const float* z = logits + (size_t)row * VP;

  for (int i = tid; i < NB; i += 1024) bins[i] = 0.0;
  if (tid == 0) { ccount = 0; sh_chunk = -1; sh_bstar = -1; }
  __syncthreads();

  // pass 1: row max
  float mx = -3.4e38f;
  for (int i = tid; i < VV; i += 1024) mx = fmaxf(mx, z[i]);
  sf[tid] = mx; __syncthreads();
  for (int s = 512; s > 0; s >>= 1) {
    if (tid < s) sf[tid] = fmaxf(sf[tid], sf[tid + s]);
    __syncthreads();
  }
  const float m = sf[0];
  __syncthreads();

  // pass 2: histogram of exp(z-m) binned by (m-z)*256
  for (int i = tid; i < VV; i += 1024) {
    float zi = z[i];
    int bin = (int)((m - zi) * 256.0f);
    bin = (bin < 0) ? 0 : ((bin > NB - 1) ? NB - 1 : bin);
    atomicAdd(&bins[bin], (double)expf(zi - m));
  }
  __syncthreads();

  // inclusive scan over 1024 chunk-sums (4 bins/chunk), f64
  {
    double c = bins[4 * tid] + bins[4 * tid + 1] + bins[4 * tid + 2] + bins[4 * tid + 3];
    sd[tid] = c; __syncthreads();
    for (int off = 1; off < 1024; off <<= 1) {
      double vv = (tid >= off) ? sd[tid - off] : 0.0;
      __syncthreads();
      sd[tid] += vv;
      __syncthreads();
    }
  }
  const double Z = sd[1023];
  const double C = (double)0.9f * Z;

  if (sd[tid] > C && (tid == 0 || sd[tid - 1] <= C)) sh_chunk = tid;
  __syncthreads();
  if (tid == 0) {
    int tc = sh_chunk;
    if (tc >= 0) {
      double run = (tc > 0) ? sd[tc - 1] : 0.0;
      for (int k = 0; k < 4; ++k) {
        double bw = bins[4 * tc + k];
        if (run + bw > C) { sh_bstar = 4 * tc + k; sh_sabove = run; break; }
        run += bw;
      }
    }
  }
  __syncthreads();
  const int bstar = sh_bstar;
  unsigned tkey = 0u;

  if (bstar >= 0) {
    const double Sab = sh_sabove;
    // pass 3: collect boundary-bin elements
    for (int i = tid; i < VV; i += 1024) {
      float zi = z[i];
      int bin = (int)((m - zi) * 256.0f);
      bin = (bin < 0) ? 0 : ((bin > NB - 1) ? NB - 1 : bin);
      if (bin == bstar) {
        int slot = atomicAdd(&ccount, 1);
        if (slot < MAXC) {
          ckey[slot] = mono_key(zi);
          cidx[slot] = i;
          cw[slot] = (double)expf(zi - m);
        }
      }
    }
    __syncthreads();
    int n = ccount; if (n > MAXC) n = MAXC;
    // kept iff exclusive prefix (in (key desc, idx asc) order) <= C
    unsigned mk = 0xFFFFFFFFu;
    for (int i = tid; i < n; i += 1024) {
      unsigned ki = ckey[i]; int ii = cidx[i];
      double T = Sab;
      for (int j = 0; j < n; ++j) {
        unsigned kj = ckey[j];
        if (kj > ki || (kj == ki && cidx[j] < ii)) T += cw[j];
      }
      if (T <= C) mk = (ki < mk) ? ki : mk;
    }
    su[tid] = mk; __syncthreads();
    for (int s = 512; s > 0; s >>= 1) {
      if (tid < s) su[tid] = min(su[tid], su[tid + s]);
      __syncthreads();
    }
    tkey = su[0];
  }
  if (tid == 0) { tstar_out[row] = tkey; pack[row] = 0ull; }
}

// Gumbel argmax over kept tokens, 8 blocks/row; combine via atomicMax(u64)
// on pack = mono(best)<<32 | (~idx) — order-independent (deterministic) and
// reproduces (best desc, idx asc) tie-break exactly.
__global__ __launch_bounds__(1024) void gumbel_kernel(
    const float* __restrict__ logits, const unsigned* __restrict__ tstar_arr,
    unsigned long long* __restrict__ pack) {
  __shared__ float sf[1024];
  __shared__ int si[1024];
  const int row = blockIdx.x >> 3;
  const int q = blockIdx.x & 7;
  const int tid = threadIdx.x;
  const unsigned tstar = tstar_arr[row];
  const float* z = logits + (size_t)row * VP;
  const int i0 = q * QCH;
  const int i1 = (i0 + QCH < VV) ? (i0 + QCH) : VV;

  float best = -3.4e38f; int bidx = 0x7FFFFFFF;
  for (int i = i0 + tid; i < i1; i += 1024) {
    float zi = z[i];
    if (mono_key(zi) < tstar) continue;
    unsigned e = (unsigned)row * (unsigned)VV + (unsigned)i;   // logical VV!
    unsigned bits = jax_random_bits(e);
    float f = __uint_as_float((bits >> 9) | 0x3F800000u) - 1.0f;
    float u = fmaxf(1.17549435082228750797e-38f, f);
    float g = -logf(-logf(u));
    float sc = zi + g;
    if (sc > best) { best = sc; bidx = i; }
  }
  sf[tid] = best; si[tid] = bidx; __syncthreads();
  for (int s = 512; s > 0; s >>= 1) {
    if (tid < s) {
      float ob = sf[tid + s]; int oi = si[tid + s];
      if (ob > sf[tid] || (ob == sf[tid] && oi < si[tid])) {
        sf[tid] = ob; si[tid] = oi;
      }
    }
    __syncthreads();
  }
  if (tid == 0 && si[0] != 0x7FFFFFFF) {
    unsigned long long p = ((unsigned long long)mono_key(sf[0]) << 32) |
                           (unsigned long long)(0xFFFFFFFFu - (unsigned)si[0]);
    atomicMax(pack + row, p);
  }
}

__global__ __launch_bounds__(64) void unpack_kernel(
    const unsigned long long* __restrict__ pack, int* __restrict__ out) {
  int r = threadIdx.x;
  if (r < BB) out[r] = (int)(0xFFFFFFFFu - (unsigned)(pack[r] & 0xFFFFFFFFull));
}

extern "C" void kernel_launch(void* const* d_in, const int* in_sizes, int n_in,
                              void* d_out, int out_size, void* d_ws, size_t ws_size,
                              hipStream_t stream) {
  const float* x = (const float*)d_in[0];
  const float* W = (const float*)d_in[1];
  const float* bias = (const float*)d_in[2];
  int* out = (int*)d_out;
  char* ws = (char*)d_ws;

  unsigned short* xh = (unsigned short*)ws;              // 262144 B
  unsigned short* xl = (unsigned short*)(ws + 262144);   // 262144 B
  float* logits = (float*)(ws + 524288);                 // BB*VP*4 = 12866560
  unsigned* tstar = (unsigned*)(ws + 13390848);          // 256 B
  unsigned long long* pack = (unsigned long long*)(ws + 13391104);  // 512 B

  pack_x_kernel<<<64, 256, 0, stream>>>(x, xh, xl);
  const int cblocks = (VV + 63) / 64;   // 786 col-blocks of 64 cols
  gemm_mfma_kernel<<<cblocks, 256, 0, stream>>>(xh, xl, W, bias, logits);
  nucleus_tstar_kernel<<<BB, 1024, 0, stream>>>(logits, tstar, pack);
  gumbel_kernel<<<BB * QS, 1024, 0, stream>>>(logits, tstar, pack);
  unpack_kernel<<<1, 64, 0, stream>>>(pack, out);
}